// Round 4
// baseline (377.932 us; speedup 1.0000x reference)
//
#include <hip/hip_runtime.h>
#include <math.h>

// CausalSelfAttention w/ KV cache, MI355X gfx950.
// B=8 T=64 C=2048 H=16 hd=128 S=4096 -> SKV=4160. All device I/O is FLOAT32.
// Internals: bf16 MFMA (16x16x32), f32 accumulate.
// R4 changes: __syncthreads -> lgkmcnt-only barrier (no vmcnt drain; copy
// stores + prefetch loads stay in flight across tiles, T3/T4 lesson);
// attn K/V register double-buffer w/ 2-tile unroll; nseg 10->13;
// GEMM grid transposed so same-W m-blocks share an XCD.

typedef __attribute__((ext_vector_type(4))) float f32x4;
typedef __attribute__((ext_vector_type(8))) short s16x8;
typedef __attribute__((ext_vector_type(2))) unsigned int u32x2;
typedef __attribute__((ext_vector_type(4))) unsigned int u32x4;

#define MFMA_BF16(A_, B_, C_) __builtin_amdgcn_mfma_f32_16x16x32_bf16((A_), (B_), (C_), 0, 0, 0)

__device__ __forceinline__ unsigned short f2bf(float f) {
  unsigned int u = __builtin_bit_cast(unsigned int, f);
  u += 0x7FFFu + ((u >> 16) & 1u);
  return (unsigned short)(u >> 16);
}
__device__ __forceinline__ unsigned int pack2(float a, float b) {
  return (unsigned int)f2bf(a) | ((unsigned int)f2bf(b) << 16);
}
// Barrier with LDS-visibility only: does NOT drain vmcnt, so global loads
// (prefetch) and stores (cache copy) pipeline across tiles.
__device__ __forceinline__ void lds_barrier() {
  asm volatile("s_waitcnt lgkmcnt(0)" ::: "memory");
  __builtin_amdgcn_s_barrier();
}

// ---------------------------------------------------------------------------
// GEMM: C[m][n] = sum_k A[m][k]*W[k][n]. M=512, K=2048, N=ncols. A,W f32.
// BM x 128 tile, 4 waves (2x2), register-prefetched k-steps of 64.
// grid = dim3(N/128, M/BM): same-W m-blocks are 16/48 apart in linear ID
// (multiple of 8) -> same XCD -> W panel L2-reuse.
// mode 0 (qkv, BM=128, ncols=6144): n<2048 -> qws (bf16 * QSCALE, [B,H,T,hd]);
//   2048..4095 -> kout tail rows 4096..4159 (f32); >=4096 -> vout tail (f32).
// mode 1 (proj, BM=64, ncols=2048): f32 store to yout[512][2048].
// ---------------------------------------------------------------------------
constexpr float QSCALE = 0.08838834764831845f * 1.4426950408889634f; // 1/sqrt(128)*log2e

template <int BM>
__global__ __launch_bounds__(256) void gemm_kernel(
    const float* __restrict__ A, const float* __restrict__ W,
    int ncols, int mode,
    unsigned short* __restrict__ qws, float* __restrict__ kout,
    float* __restrict__ vout, float* __restrict__ yout)
{
  constexpr int MI = BM / 32;          // m-frags per wave
  constexpr int AIT = BM / 32;         // A staging iters (32 rows each)
  __shared__ __align__(16) unsigned short Alds[BM][72];
  __shared__ __align__(16) unsigned short Blds[128][72]; // [n][k], k chunk-XOR swizzled

  const int tid = threadIdx.x;
  const int w = tid >> 6, l = tid & 63;
  const int lr = l & 15, lg = l >> 4;
  const int n0 = blockIdx.x * 128;
  const int m0 = blockIdx.y * BM;
  const int wm = (w >> 1) * (BM / 2), wn = (w & 1) * 64;

  const int arow = tid >> 3, acol = (tid & 7) << 3;
  const int bkp = tid >> 4, bcol = (tid & 15) << 3;
  const int bswz = ((bcol >> 3) & 7) << 3;

  f32x4 ar[AIT][2];
  f32x4 br[2][4];

  auto loadA = [&](int k0) {
#pragma unroll
    for (int it = 0; it < AIT; ++it) {
      const float* pa = A + (size_t)(m0 + it * 32 + arow) * 2048 + k0 + acol;
      ar[it][0] = *(const f32x4*)pa;
      ar[it][1] = *(const f32x4*)(pa + 4);
    }
  };
  auto loadB = [&](int k0) {
#pragma unroll
    for (int i = 0; i < 2; ++i) {
      const int krow = 2 * (i * 16 + bkp);
      const float* pw = W + (size_t)(k0 + krow) * ncols + n0 + bcol;
      br[i][0] = *(const f32x4*)pw;
      br[i][1] = *(const f32x4*)(pw + 4);
      br[i][2] = *(const f32x4*)(pw + ncols);
      br[i][3] = *(const f32x4*)(pw + ncols + 4);
    }
  };

  f32x4 acc[MI][4] = {};

  loadA(0); loadB(0);
  for (int ks = 0; ks < 32; ++ks) {
    // regs -> LDS (bf16)
#pragma unroll
    for (int it = 0; it < AIT; ++it) {
      u32x4 p;
      p[0] = pack2(ar[it][0][0], ar[it][0][1]); p[1] = pack2(ar[it][0][2], ar[it][0][3]);
      p[2] = pack2(ar[it][1][0], ar[it][1][1]); p[3] = pack2(ar[it][1][2], ar[it][1][3]);
      *(u32x4*)(&Alds[it * 32 + arow][acol]) = p;
    }
#pragma unroll
    for (int i = 0; i < 2; ++i) {
      const int krow = 2 * (i * 16 + bkp);
      const int kc = krow ^ bswz;   // bswz touches bits>=3 only: kc,kc+1 adjacent
#pragma unroll
      for (int j = 0; j < 8; ++j) {
        const float v0 = (j < 4) ? br[i][0][j] : br[i][1][j - 4];
        const float v1 = (j < 4) ? br[i][2][j] : br[i][3][j - 4];
        *(unsigned int*)(&Blds[bcol + j][kc]) = pack2(v0, v1);
      }
    }
    lds_barrier();

    if (ks < 31) { loadA((ks + 1) * 64); loadB((ks + 1) * 64); } // stays in flight

    s16x8 af[MI][2], bfr[4][2];
#pragma unroll
    for (int mi = 0; mi < MI; ++mi)
#pragma unroll
      for (int kk = 0; kk < 2; ++kk)
        af[mi][kk] = *(const s16x8*)(&Alds[wm + mi * 16 + lr][kk * 32 + lg * 8]);
#pragma unroll
    for (int ni = 0; ni < 4; ++ni) {
      const int n = wn + ni * 16 + lr;
      const int nswz = ((n >> 3) & 7) << 3;
#pragma unroll
      for (int kk = 0; kk < 2; ++kk)
        bfr[ni][kk] = *(const s16x8*)(&Blds[n][(kk * 32 + lg * 8) ^ nswz]);
    }
#pragma unroll
    for (int kk = 0; kk < 2; ++kk)
#pragma unroll
      for (int mi = 0; mi < MI; ++mi)
#pragma unroll
        for (int ni = 0; ni < 4; ++ni)
          acc[mi][ni] = MFMA_BF16(af[mi][kk], bfr[ni][kk], acc[mi][ni]);
    lds_barrier();
  }

  if (mode == 0) {
    const int which = n0 >> 11;          // 0=q 1=k 2=v (BN=128 == one head)
    const int h = (n0 >> 7) & 15;
    float* kv = (which == 1) ? kout : vout;
#pragma unroll
    for (int mi = 0; mi < MI; ++mi)
#pragma unroll
      for (int ni = 0; ni < 4; ++ni) {
        const int d = wn + ni * 16 + lr;
#pragma unroll
        for (int r = 0; r < 4; ++r) {
          const int mg = m0 + wm + mi * 16 + lg * 4 + r;
          const int b = mg >> 6, t = mg & 63;
          const float val = acc[mi][ni][r];
          if (which == 0)
            qws[(((size_t)(b * 16 + h) * 64 + t) << 7) + d] = f2bf(val * QSCALE);
          else
            kv[((size_t)(b * 16 + h) * 4160 + 4096 + t) * 128 + d] = val;
        }
      }
  } else {
#pragma unroll
    for (int mi = 0; mi < MI; ++mi)
#pragma unroll
      for (int ni = 0; ni < 4; ++ni) {
        const int n = n0 + wn + ni * 16 + lr;
#pragma unroll
        for (int r = 0; r < 4; ++r) {
          const int mg = m0 + wm + mi * 16 + lg * 4 + r;
          yout[(size_t)mg * 2048 + n] = acc[mi][ni][r];
        }
      }
  }
}

// ---------------------------------------------------------------------------
// Fused KV-cache copy + flash attention (partial, per key segment).
// Block = (bh, seg): 4 waves, wave w owns queries w*16..w*16+15.
// Register-double-buffered K/V tiles (A/B), lgkm-only barriers: copy stores
// and next-tile loads pipeline across tile boundaries. ntiles must be EVEN.
// ---------------------------------------------------------------------------
__global__ __launch_bounds__(256) void attn_kernel(
    const float* __restrict__ pastk, const float* __restrict__ pastv,
    const unsigned short* __restrict__ qws,
    float* __restrict__ kout, float* __restrict__ vout,
    float* __restrict__ Ows, float* __restrict__ mlws,
    int nseg, int seglen, int ntiles)
{
  __shared__ __align__(16) unsigned short Klds[32][136]; // +8 pad
  __shared__ __align__(16) unsigned short VT[128][32];   // [d][k ^ ((d>>3)&3)<<3]
  __shared__ __align__(16) unsigned short Plds[4][16][40];

  const int tid = threadIdx.x;
  const int w = tid >> 6, l = tid & 63;
  const int lr = l & 15, lg = l >> 4;
  const int bh = blockIdx.x / nseg;
  const int seg = blockIdx.x % nseg;
  const int segbase = seg * seglen;

  s16x8 qf[4];
  {
    const unsigned short* qb = qws + ((size_t)bh * 64 + w * 16 + lr) * 128 + lg * 8;
#pragma unroll
    for (int kk = 0; kk < 4; ++kk) qf[kk] = *(const s16x8*)(qb + kk * 32);
  }

  float mrow[4] = {-INFINITY, -INFINITY, -INFINITY, -INFINITY};
  float lrowv[4] = {0.f, 0.f, 0.f, 0.f};
  f32x4 Oacc[8] = {};

  const int skr = tid >> 3;        // key row in tile (0..31)
  const int sd = (tid & 7) << 2;   // interleaved: lane covers floats sd+32c+{0..3}

  f32x4 kvA[4], vvA[4], kvB[4], vvB[4];
  int sA = 0, sB = 0; size_t ooA = 0, ooB = 0;

  auto load_tile = [&](int t, f32x4 (&kvr)[4], f32x4 (&vvr)[4], int& sr, size_t& oor) {
    const int s = segbase + t * 32 + skr;
    const size_t oo = ((size_t)bh * 4160 + s) * 128 + sd;
    sr = s; oor = oo;
    if (s < 4096) {
      const float* a = pastk + ((size_t)bh * 4096 + s) * 128 + sd;
      const float* b = pastv + ((size_t)bh * 4096 + s) * 128 + sd;
#pragma unroll
      for (int c = 0; c < 4; ++c) { kvr[c] = *(const f32x4*)(a + 32 * c); vvr[c] = *(const f32x4*)(b + 32 * c); }
    } else {
#pragma unroll
      for (int c = 0; c < 4; ++c) { kvr[c] = *(const f32x4*)(kout + oo + 32 * c); vvr[c] = *(const f32x4*)(vout + oo + 32 * c); }
    }
  };
  auto convert_tile = [&](const f32x4 (&kvr)[4], const f32x4 (&vvr)[4]) {
#pragma unroll
    for (int c = 0; c < 4; ++c) {
      const int d0 = sd + 32 * c;
      u32x2 pk;
      pk[0] = pack2(kvr[c][0], kvr[c][1]);
      pk[1] = pack2(kvr[c][2], kvr[c][3]);
      *(u32x2*)(&Klds[skr][d0]) = pk;
#pragma unroll
      for (int e = 0; e < 4; ++e) {
        const int d = d0 + e;
        VT[d][skr ^ (((d >> 3) & 3) << 3)] = f2bf(vvr[c][e]);
      }
    }
  };
  auto copy_store = [&](const f32x4 (&kvr)[4], const f32x4 (&vvr)[4], size_t oo) {
    float* ko = kout + oo; float* vo = vout + oo;
#pragma unroll
    for (int c = 0; c < 4; ++c) { *(f32x4*)(ko + 32 * c) = kvr[c]; *(f32x4*)(vo + 32 * c) = vvr[c]; }
  };
  auto compute_tile = [&]() {
    f32x4 sc[2] = {};
#pragma unroll
    for (int kk = 0; kk < 4; ++kk)
#pragma unroll
      for (int st = 0; st < 2; ++st) {
        s16x8 kf = *(const s16x8*)(&Klds[st * 16 + lr][kk * 32 + lg * 8]);
        sc[st] = MFMA_BF16(qf[kk], kf, sc[st]);
      }
#pragma unroll
    for (int r = 0; r < 4; ++r) {
      float tm = fmaxf(sc[0][r], sc[1][r]);
      tm = fmaxf(tm, __shfl_xor(tm, 1));
      tm = fmaxf(tm, __shfl_xor(tm, 2));
      tm = fmaxf(tm, __shfl_xor(tm, 4));
      tm = fmaxf(tm, __shfl_xor(tm, 8));
      const float mn = fmaxf(mrow[r], tm);
      const float alpha = exp2f(mrow[r] - mn);
      mrow[r] = mn;
      const float p0f = exp2f(sc[0][r] - mn);
      const float p1f = exp2f(sc[1][r] - mn);
      float rs = p0f + p1f;
      rs += __shfl_xor(rs, 1);
      rs += __shfl_xor(rs, 2);
      rs += __shfl_xor(rs, 4);
      rs += __shfl_xor(rs, 8);
      lrowv[r] = lrowv[r] * alpha + rs;
#pragma unroll
      for (int dt = 0; dt < 8; ++dt) Oacc[dt][r] *= alpha;
      Plds[w][lg * 4 + r][lr] = f2bf(p0f);
      Plds[w][lg * 4 + r][16 + lr] = f2bf(p1f);
    }
    s16x8 pf = *(const s16x8*)(&Plds[w][lr][lg * 8]);
#pragma unroll
    for (int dt = 0; dt < 8; ++dt) {
      const int d = dt * 16 + lr;
      s16x8 vf = *(const s16x8*)(&VT[d][(lg * 8) ^ (((d >> 3) & 3) << 3)]);
      Oacc[dt] = MFMA_BF16(pf, vf, Oacc[dt]);
    }
  };

  load_tile(0, kvA, vvA, sA, ooA);
  for (int tt = 0; tt < ntiles; tt += 2) {
    // ---- tile tt (A regs)
    convert_tile(kvA, vvA);
    lds_barrier();
    if (sA < 4096) copy_store(kvA, vvA, ooA);
    if (tt + 1 < ntiles) load_tile(tt + 1, kvB, vvB, sB, ooB);
    compute_tile();
    lds_barrier();
    // ---- tile tt+1 (B regs)
    convert_tile(kvB, vvB);
    lds_barrier();
    if (sB < 4096) copy_store(kvB, vvB, ooB);
    if (tt + 2 < ntiles) load_tile(tt + 2, kvA, vvA, sA, ooA);
    compute_tile();
    lds_barrier();
  }

  const size_t rowbase = ((size_t)seg * 128 + bh) * 64 + w * 16;
#pragma unroll
  for (int dt = 0; dt < 8; ++dt)
#pragma unroll
    for (int r = 0; r < 4; ++r)
      Ows[(rowbase + lg * 4 + r) * 128 + dt * 16 + lr] = Oacc[dt][r];
  if (lr == 0) {
#pragma unroll
    for (int r = 0; r < 4; ++r) {
      const size_t mi = rowbase + lg * 4 + r;
      mlws[mi * 2 + 0] = mrow[r];
      mlws[mi * 2 + 1] = lrowv[r];
    }
  }
}

// ---------------------------------------------------------------------------
// Merge nseg partials -> yhead[(b*64+q)][h*128+d] (f32 [512][2048]).
// ---------------------------------------------------------------------------
__global__ __launch_bounds__(256) void combine_kernel(
    const float* __restrict__ Ows, const float* __restrict__ mlws,
    float* __restrict__ yhead, int nseg)
{
  const int idx = blockIdx.x * 256 + threadIdx.x;
  const int d = idx & 127;
  const int row = idx >> 7;            // bh*64+q, 0..8191
  float M = -INFINITY;
  for (int s = 0; s < nseg; ++s) M = fmaxf(M, mlws[((size_t)s * 8192 + row) * 2]);
  float num = 0.f, den = 0.f;
  for (int s = 0; s < nseg; ++s) {
    const size_t r = (size_t)s * 8192 + row;
    const float wgt = exp2f(mlws[r * 2] - M);
    den += wgt * mlws[r * 2 + 1];
    num += wgt * Ows[r * 128 + d];
  }
  const float o = num / den;
  const int bh = row >> 6, q = row & 63;
  const int b = bh >> 4, h = bh & 15;
  yhead[(size_t)(b * 64 + q) * 2048 + h * 128 + d] = o;
}

// ---------------------------------------------------------------------------
extern "C" void kernel_launch(void* const* d_in, const int* in_sizes, int n_in,
                              void* d_out, int out_size, void* d_ws, size_t ws_size,
                              hipStream_t stream)
{
  (void)in_sizes; (void)n_in; (void)out_size;
  const float* x  = (const float*)d_in[0];
  const float* pk = (const float*)d_in[1];
  const float* pv = (const float*)d_in[2];
  const float* wa = (const float*)d_in[3];
  const float* wp = (const float*)d_in[4];

  float* out  = (float*)d_out;
  float* y    = out;                          // 1,048,576
  float* kout = out + 1048576;                // 68,157,440
  float* vout = out + 1048576 + 68157440;     // 68,157,440

  char* ws = (char*)d_ws;
  unsigned short* qws = (unsigned short*)(ws);                      // 2 MiB bf16
  float* yhead = (float*)(ws + ((size_t)2 << 20));                  // 4 MiB f32
  float* mlws  = (float*)(ws + ((size_t)6 << 20));                  // <=852 KiB
  float* Ows   = (float*)(ws + ((size_t)7 << 20));                  // nseg*4 MiB

  const size_t base = (size_t)7 << 20;
  // ntiles (= seglen/32) must be EVEN for the 2-tile unroll: 13->10, 5->26, 1->130.
  int nseg = 1;
  if (ws_size >= base + (size_t)13 * 4194304) nseg = 13;     // 1664 blocks, 6.5/CU
  else if (ws_size >= base + (size_t)5 * 4194304) nseg = 5;
  const int seglen = 4160 / nseg;
  const int ntiles = seglen / 32;

  gemm_kernel<128><<<dim3(48, 4), dim3(256), 0, stream>>>(x, wa, 6144, 0, qws, kout, vout, nullptr);
  attn_kernel<<<dim3(128 * nseg), dim3(256), 0, stream>>>(pk, pv, qws, kout, vout, Ows, mlws,
                                                          nseg, seglen, ntiles);
  combine_kernel<<<dim3(4096), dim3(256), 0, stream>>>(Ows, mlws, yhead, nseg);
  gemm_kernel<64><<<dim3(16, 8), dim3(256), 0, stream>>>(yhead, wp, 2048, 1, nullptr, nullptr, nullptr, y);
}

// Round 5
// 344.256 us; speedup vs baseline: 1.0978x; 1.0978x over previous
//
#include <hip/hip_runtime.h>
#include <math.h>

// CausalSelfAttention w/ KV cache, MI355X gfx950.
// B=8 T=64 C=2048 H=16 hd=128 S=4096 -> SKV=4160. All device I/O is FLOAT32.
// Internals: bf16 MFMA (16x16x32), f32 accumulate.
// R5 (attribution round): attn kernel UNCHANGED from R4. qkv GEMM BM 128->64
// (384 blocks), proj GEMM BM 64->32 (256 blocks), combine vectorized x4.

typedef __attribute__((ext_vector_type(4))) float f32x4;
typedef __attribute__((ext_vector_type(8))) short s16x8;
typedef __attribute__((ext_vector_type(2))) unsigned int u32x2;
typedef __attribute__((ext_vector_type(4))) unsigned int u32x4;

#define MFMA_BF16(A_, B_, C_) __builtin_amdgcn_mfma_f32_16x16x32_bf16((A_), (B_), (C_), 0, 0, 0)

__device__ __forceinline__ unsigned short f2bf(float f) {
  unsigned int u = __builtin_bit_cast(unsigned int, f);
  u += 0x7FFFu + ((u >> 16) & 1u);
  return (unsigned short)(u >> 16);
}
__device__ __forceinline__ unsigned int pack2(float a, float b) {
  return (unsigned int)f2bf(a) | ((unsigned int)f2bf(b) << 16);
}
// Barrier with LDS-visibility only: does NOT drain vmcnt.
__device__ __forceinline__ void lds_barrier() {
  asm volatile("s_waitcnt lgkmcnt(0)" ::: "memory");
  __builtin_amdgcn_s_barrier();
}

// ---------------------------------------------------------------------------
// GEMM: C[m][n] = sum_k A[m][k]*W[k][n]. M=512, K=2048, N=ncols. A,W f32.
// BM x 128 tile, 4 waves (2x2), register-prefetched k-steps of 64.
// mode 0 (qkv, BM=64, ncols=6144): n<2048 -> qws (bf16 * QSCALE, [B,H,T,hd]);
//   2048..4095 -> kout tail rows 4096..4159 (f32); >=4096 -> vout tail (f32).
// mode 1 (proj, BM=32, ncols=2048): f32 store to yout[512][2048].
// ---------------------------------------------------------------------------
constexpr float QSCALE = 0.08838834764831845f * 1.4426950408889634f; // 1/sqrt(128)*log2e

template <int BM>
__global__ __launch_bounds__(256) void gemm_kernel(
    const float* __restrict__ A, const float* __restrict__ W,
    int ncols, int mode,
    unsigned short* __restrict__ qws, float* __restrict__ kout,
    float* __restrict__ vout, float* __restrict__ yout)
{
  constexpr int MI = BM / 32;          // m-frags per wave
  constexpr int AIT = BM / 32;         // A staging iters (32 rows each)
  __shared__ __align__(16) unsigned short Alds[BM][72];
  __shared__ __align__(16) unsigned short Blds[128][72]; // [n][k], k chunk-XOR swizzled

  const int tid = threadIdx.x;
  const int w = tid >> 6, l = tid & 63;
  const int lr = l & 15, lg = l >> 4;
  const int n0 = blockIdx.x * 128;
  const int m0 = blockIdx.y * BM;
  const int wm = (w >> 1) * (BM / 2), wn = (w & 1) * 64;

  const int arow = tid >> 3, acol = (tid & 7) << 3;
  const int bkp = tid >> 4, bcol = (tid & 15) << 3;
  const int bswz = ((bcol >> 3) & 7) << 3;

  f32x4 ar[AIT][2];
  f32x4 br[2][4];

  auto loadA = [&](int k0) {
#pragma unroll
    for (int it = 0; it < AIT; ++it) {
      const float* pa = A + (size_t)(m0 + it * 32 + arow) * 2048 + k0 + acol;
      ar[it][0] = *(const f32x4*)pa;
      ar[it][1] = *(const f32x4*)(pa + 4);
    }
  };
  auto loadB = [&](int k0) {
#pragma unroll
    for (int i = 0; i < 2; ++i) {
      const int krow = 2 * (i * 16 + bkp);
      const float* pw = W + (size_t)(k0 + krow) * ncols + n0 + bcol;
      br[i][0] = *(const f32x4*)pw;
      br[i][1] = *(const f32x4*)(pw + 4);
      br[i][2] = *(const f32x4*)(pw + ncols);
      br[i][3] = *(const f32x4*)(pw + ncols + 4);
    }
  };

  f32x4 acc[MI][4] = {};

  loadA(0); loadB(0);
  for (int ks = 0; ks < 32; ++ks) {
    // regs -> LDS (bf16)
#pragma unroll
    for (int it = 0; it < AIT; ++it) {
      u32x4 p;
      p[0] = pack2(ar[it][0][0], ar[it][0][1]); p[1] = pack2(ar[it][0][2], ar[it][0][3]);
      p[2] = pack2(ar[it][1][0], ar[it][1][1]); p[3] = pack2(ar[it][1][2], ar[it][1][3]);
      *(u32x4*)(&Alds[it * 32 + arow][acol]) = p;
    }
#pragma unroll
    for (int i = 0; i < 2; ++i) {
      const int krow = 2 * (i * 16 + bkp);
      const int kc = krow ^ bswz;   // bswz touches bits>=3 only: kc,kc+1 adjacent
#pragma unroll
      for (int j = 0; j < 8; ++j) {
        const float v0 = (j < 4) ? br[i][0][j] : br[i][1][j - 4];
        const float v1 = (j < 4) ? br[i][2][j] : br[i][3][j - 4];
        *(unsigned int*)(&Blds[bcol + j][kc]) = pack2(v0, v1);
      }
    }
    lds_barrier();

    if (ks < 31) { loadA((ks + 1) * 64); loadB((ks + 1) * 64); } // stays in flight

    s16x8 af[MI][2], bfr[4][2];
#pragma unroll
    for (int mi = 0; mi < MI; ++mi)
#pragma unroll
      for (int kk = 0; kk < 2; ++kk)
        af[mi][kk] = *(const s16x8*)(&Alds[wm + mi * 16 + lr][kk * 32 + lg * 8]);
#pragma unroll
    for (int ni = 0; ni < 4; ++ni) {
      const int n = wn + ni * 16 + lr;
      const int nswz = ((n >> 3) & 7) << 3;
#pragma unroll
      for (int kk = 0; kk < 2; ++kk)
        bfr[ni][kk] = *(const s16x8*)(&Blds[n][(kk * 32 + lg * 8) ^ nswz]);
    }
#pragma unroll
    for (int kk = 0; kk < 2; ++kk)
#pragma unroll
      for (int mi = 0; mi < MI; ++mi)
#pragma unroll
        for (int ni = 0; ni < 4; ++ni)
          acc[mi][ni] = MFMA_BF16(af[mi][kk], bfr[ni][kk], acc[mi][ni]);
    lds_barrier();
  }

  if (mode == 0) {
    const int which = n0 >> 11;          // 0=q 1=k 2=v (BN=128 == one head)
    const int h = (n0 >> 7) & 15;
    float* kv = (which == 1) ? kout : vout;
#pragma unroll
    for (int mi = 0; mi < MI; ++mi)
#pragma unroll
      for (int ni = 0; ni < 4; ++ni) {
        const int d = wn + ni * 16 + lr;
#pragma unroll
        for (int r = 0; r < 4; ++r) {
          const int mg = m0 + wm + mi * 16 + lg * 4 + r;
          const int b = mg >> 6, t = mg & 63;
          const float val = acc[mi][ni][r];
          if (which == 0)
            qws[(((size_t)(b * 16 + h) * 64 + t) << 7) + d] = f2bf(val * QSCALE);
          else
            kv[((size_t)(b * 16 + h) * 4160 + 4096 + t) * 128 + d] = val;
        }
      }
  } else {
#pragma unroll
    for (int mi = 0; mi < MI; ++mi)
#pragma unroll
      for (int ni = 0; ni < 4; ++ni) {
        const int n = n0 + wn + ni * 16 + lr;
#pragma unroll
        for (int r = 0; r < 4; ++r) {
          const int mg = m0 + wm + mi * 16 + lg * 4 + r;
          yout[(size_t)mg * 2048 + n] = acc[mi][ni][r];
        }
      }
  }
}

// ---------------------------------------------------------------------------
// Fused KV-cache copy + flash attention (partial, per key segment).
// UNCHANGED from R4 (attribution round).
// ---------------------------------------------------------------------------
__global__ __launch_bounds__(256) void attn_kernel(
    const float* __restrict__ pastk, const float* __restrict__ pastv,
    const unsigned short* __restrict__ qws,
    float* __restrict__ kout, float* __restrict__ vout,
    float* __restrict__ Ows, float* __restrict__ mlws,
    int nseg, int seglen, int ntiles)
{
  __shared__ __align__(16) unsigned short Klds[32][136]; // +8 pad
  __shared__ __align__(16) unsigned short VT[128][32];   // [d][k ^ ((d>>3)&3)<<3]
  __shared__ __align__(16) unsigned short Plds[4][16][40];

  const int tid = threadIdx.x;
  const int w = tid >> 6, l = tid & 63;
  const int lr = l & 15, lg = l >> 4;
  const int bh = blockIdx.x / nseg;
  const int seg = blockIdx.x % nseg;
  const int segbase = seg * seglen;

  s16x8 qf[4];
  {
    const unsigned short* qb = qws + ((size_t)bh * 64 + w * 16 + lr) * 128 + lg * 8;
#pragma unroll
    for (int kk = 0; kk < 4; ++kk) qf[kk] = *(const s16x8*)(qb + kk * 32);
  }

  float mrow[4] = {-INFINITY, -INFINITY, -INFINITY, -INFINITY};
  float lrowv[4] = {0.f, 0.f, 0.f, 0.f};
  f32x4 Oacc[8] = {};

  const int skr = tid >> 3;        // key row in tile (0..31)
  const int sd = (tid & 7) << 2;   // interleaved: lane covers floats sd+32c+{0..3}

  f32x4 kvA[4], vvA[4], kvB[4], vvB[4];
  int sA = 0, sB = 0; size_t ooA = 0, ooB = 0;

  auto load_tile = [&](int t, f32x4 (&kvr)[4], f32x4 (&vvr)[4], int& sr, size_t& oor) {
    const int s = segbase + t * 32 + skr;
    const size_t oo = ((size_t)bh * 4160 + s) * 128 + sd;
    sr = s; oor = oo;
    if (s < 4096) {
      const float* a = pastk + ((size_t)bh * 4096 + s) * 128 + sd;
      const float* b = pastv + ((size_t)bh * 4096 + s) * 128 + sd;
#pragma unroll
      for (int c = 0; c < 4; ++c) { kvr[c] = *(const f32x4*)(a + 32 * c); vvr[c] = *(const f32x4*)(b + 32 * c); }
    } else {
#pragma unroll
      for (int c = 0; c < 4; ++c) { kvr[c] = *(const f32x4*)(kout + oo + 32 * c); vvr[c] = *(const f32x4*)(vout + oo + 32 * c); }
    }
  };
  auto convert_tile = [&](const f32x4 (&kvr)[4], const f32x4 (&vvr)[4]) {
#pragma unroll
    for (int c = 0; c < 4; ++c) {
      const int d0 = sd + 32 * c;
      u32x2 pk;
      pk[0] = pack2(kvr[c][0], kvr[c][1]);
      pk[1] = pack2(kvr[c][2], kvr[c][3]);
      *(u32x2*)(&Klds[skr][d0]) = pk;
#pragma unroll
      for (int e = 0; e < 4; ++e) {
        const int d = d0 + e;
        VT[d][skr ^ (((d >> 3) & 3) << 3)] = f2bf(vvr[c][e]);
      }
    }
  };
  auto copy_store = [&](const f32x4 (&kvr)[4], const f32x4 (&vvr)[4], size_t oo) {
    float* ko = kout + oo; float* vo = vout + oo;
#pragma unroll
    for (int c = 0; c < 4; ++c) { *(f32x4*)(ko + 32 * c) = kvr[c]; *(f32x4*)(vo + 32 * c) = vvr[c]; }
  };
  auto compute_tile = [&]() {
    f32x4 sc[2] = {};
#pragma unroll
    for (int kk = 0; kk < 4; ++kk)
#pragma unroll
      for (int st = 0; st < 2; ++st) {
        s16x8 kf = *(const s16x8*)(&Klds[st * 16 + lr][kk * 32 + lg * 8]);
        sc[st] = MFMA_BF16(qf[kk], kf, sc[st]);
      }
#pragma unroll
    for (int r = 0; r < 4; ++r) {
      float tm = fmaxf(sc[0][r], sc[1][r]);
      tm = fmaxf(tm, __shfl_xor(tm, 1));
      tm = fmaxf(tm, __shfl_xor(tm, 2));
      tm = fmaxf(tm, __shfl_xor(tm, 4));
      tm = fmaxf(tm, __shfl_xor(tm, 8));
      const float mn = fmaxf(mrow[r], tm);
      const float alpha = exp2f(mrow[r] - mn);
      mrow[r] = mn;
      const float p0f = exp2f(sc[0][r] - mn);
      const float p1f = exp2f(sc[1][r] - mn);
      float rs = p0f + p1f;
      rs += __shfl_xor(rs, 1);
      rs += __shfl_xor(rs, 2);
      rs += __shfl_xor(rs, 4);
      rs += __shfl_xor(rs, 8);
      lrowv[r] = lrowv[r] * alpha + rs;
#pragma unroll
      for (int dt = 0; dt < 8; ++dt) Oacc[dt][r] *= alpha;
      Plds[w][lg * 4 + r][lr] = f2bf(p0f);
      Plds[w][lg * 4 + r][16 + lr] = f2bf(p1f);
    }
    s16x8 pf = *(const s16x8*)(&Plds[w][lr][lg * 8]);
#pragma unroll
    for (int dt = 0; dt < 8; ++dt) {
      const int d = dt * 16 + lr;
      s16x8 vf = *(const s16x8*)(&VT[d][(lg * 8) ^ (((d >> 3) & 3) << 3)]);
      Oacc[dt] = MFMA_BF16(pf, vf, Oacc[dt]);
    }
  };

  load_tile(0, kvA, vvA, sA, ooA);
  for (int tt = 0; tt < ntiles; tt += 2) {
    // ---- tile tt (A regs)
    convert_tile(kvA, vvA);
    lds_barrier();
    if (sA < 4096) copy_store(kvA, vvA, ooA);
    if (tt + 1 < ntiles) load_tile(tt + 1, kvB, vvB, sB, ooB);
    compute_tile();
    lds_barrier();
    // ---- tile tt+1 (B regs)
    convert_tile(kvB, vvB);
    lds_barrier();
    if (sB < 4096) copy_store(kvB, vvB, ooB);
    if (tt + 2 < ntiles) load_tile(tt + 2, kvA, vvA, sA, ooA);
    compute_tile();
    lds_barrier();
  }

  const size_t rowbase = ((size_t)seg * 128 + bh) * 64 + w * 16;
#pragma unroll
  for (int dt = 0; dt < 8; ++dt)
#pragma unroll
    for (int r = 0; r < 4; ++r)
      Ows[(rowbase + lg * 4 + r) * 128 + dt * 16 + lr] = Oacc[dt][r];
  if (lr == 0) {
#pragma unroll
    for (int r = 0; r < 4; ++r) {
      const size_t mi = rowbase + lg * 4 + r;
      mlws[mi * 2 + 0] = mrow[r];
      mlws[mi * 2 + 1] = lrowv[r];
    }
  }
}

// ---------------------------------------------------------------------------
// Merge nseg partials -> yhead[(b*64+q)][h*128+d] (f32 [512][2048]).
// Vectorized: each thread combines 4 consecutive d via f32x4.
// grid = 8192 rows * 32 threads/row / 256 = 1024 blocks.
// ---------------------------------------------------------------------------
__global__ __launch_bounds__(256) void combine_kernel(
    const float* __restrict__ Ows, const float* __restrict__ mlws,
    float* __restrict__ yhead, int nseg)
{
  const int idx = blockIdx.x * 256 + threadIdx.x;
  const int d4 = (idx & 31) << 2;      // 0..124
  const int row = idx >> 5;            // bh*64+q, 0..8191
  float M = -INFINITY;
  for (int s = 0; s < nseg; ++s) M = fmaxf(M, mlws[((size_t)s * 8192 + row) * 2]);
  f32x4 num = {0.f, 0.f, 0.f, 0.f};
  float den = 0.f;
  for (int s = 0; s < nseg; ++s) {
    const size_t r = (size_t)s * 8192 + row;
    const float wgt = exp2f(mlws[r * 2] - M);
    den += wgt * mlws[r * 2 + 1];
    const f32x4 o4 = *(const f32x4*)(Ows + r * 128 + d4);
#pragma unroll
    for (int e = 0; e < 4; ++e) num[e] += wgt * o4[e];
  }
  const float inv = 1.0f / den;
  const int bh = row >> 6, q = row & 63;
  const int b = bh >> 4, h = bh & 15;
  float* yp = yhead + (size_t)(b * 64 + q) * 2048 + h * 128 + d4;
#pragma unroll
  for (int e = 0; e < 4; ++e) yp[e] = num[e] * inv;
}

// ---------------------------------------------------------------------------
extern "C" void kernel_launch(void* const* d_in, const int* in_sizes, int n_in,
                              void* d_out, int out_size, void* d_ws, size_t ws_size,
                              hipStream_t stream)
{
  (void)in_sizes; (void)n_in; (void)out_size;
  const float* x  = (const float*)d_in[0];
  const float* pk = (const float*)d_in[1];
  const float* pv = (const float*)d_in[2];
  const float* wa = (const float*)d_in[3];
  const float* wp = (const float*)d_in[4];

  float* out  = (float*)d_out;
  float* y    = out;                          // 1,048,576
  float* kout = out + 1048576;                // 68,157,440
  float* vout = out + 1048576 + 68157440;     // 68,157,440

  char* ws = (char*)d_ws;
  unsigned short* qws = (unsigned short*)(ws);                      // 2 MiB bf16
  float* yhead = (float*)(ws + ((size_t)2 << 20));                  // 4 MiB f32
  float* mlws  = (float*)(ws + ((size_t)6 << 20));                  // <=852 KiB
  float* Ows   = (float*)(ws + ((size_t)7 << 20));                  // nseg*4 MiB

  const size_t base = (size_t)7 << 20;
  // ntiles (= seglen/32) must be EVEN for the 2-tile unroll: 13->10, 5->26, 1->130.
  int nseg = 1;
  if (ws_size >= base + (size_t)13 * 4194304) nseg = 13;     // 1664 blocks
  else if (ws_size >= base + (size_t)5 * 4194304) nseg = 5;
  const int seglen = 4160 / nseg;
  const int ntiles = seglen / 32;

  gemm_kernel<64><<<dim3(48, 8), dim3(256), 0, stream>>>(x, wa, 6144, 0, qws, kout, vout, nullptr);
  attn_kernel<<<dim3(128 * nseg), dim3(256), 0, stream>>>(pk, pv, qws, kout, vout, Ows, mlws,
                                                          nseg, seglen, ntiles);
  combine_kernel<<<dim3(1024), dim3(256), 0, stream>>>(Ows, mlws, yhead, nseg);
  gemm_kernel<32><<<dim3(16, 16), dim3(256), 0, stream>>>(yhead, wp, 2048, 1, nullptr, nullptr, nullptr, y);
}